// Round 11
// baseline (1244.790 us; speedup 1.0000x reference)
//
#include <hip/hip_runtime.h>
#include <cstdint>
#include <cstddef>

typedef unsigned short u16;
using half4 = __attribute__((ext_vector_type(4))) _Float16;
using half8 = __attribute__((ext_vector_type(8))) _Float16;
using f32x4 = __attribute__((ext_vector_type(4))) float;
using f4    = __attribute__((ext_vector_type(4))) float;

#define B_    16
#define C_    256
#define H_    128
#define W_    128
#define C4_   64
#define COUT_ 256
#define HW_   (H_ * W_)

#define T_S       72    // kernel1 T [pixel][c-quarter]: 64 + 8 pad (octet-swizzled)
#define QK_S      72    // kernel2 Q/K [h][d]: 64 + 8 pad
#define P_S       136   // kernel2 P   [h][g]: 128 + 8 pad
#define XP_S      140   // kernel2 epilogue transpose tile [c][h]
#define O_S       72    // kernel1 out tile [pixel][d]: 64 + 8 pad

#define Q_ELEMS   ((size_t)B_ * W_ * H_ * C4_)      // 16,777,216
#define V_ELEMS   ((size_t)B_ * W_ * H_ * COUT_)    // 67,108,864
#define W16_ELEMS ((size_t)(C4_ * C_ + C4_ * C_ + COUT_ * C_))  // 98,304
#define WS_NEED   ((2 * Q_ELEMS + 2 * V_ELEMS + W16_ELEMS) * 2)

__device__ __forceinline__ u16 f16_rn(float f) {
  _Float16 h = (_Float16)f;   // RN
  return __builtin_bit_cast(u16, h);
}

__device__ __forceinline__ void gload16(const void* g, void* l) {
  __builtin_amdgcn_global_load_lds(
      (const __attribute__((address_space(1))) void*)g,
      (__attribute__((address_space(3))) void*)l, 16, 0, 0);
}

// ---------------------------------------------------------------------------
// Kernel 0: one-time fp32 -> fp16 weight conversion into ws.
// ---------------------------------------------------------------------------
__global__ void __launch_bounds__(256) wconv_kernel(
    const float* __restrict__ Wk, const float* __restrict__ Wq,
    const float* __restrict__ Wv, u16* __restrict__ W16) {
  const int bid = blockIdx.x;
  const int t   = threadIdx.x;
  const float* src;
  u16* dst;
  int idx;
  if (bid < 16)      { src = Wk; dst = W16;                 idx = bid * 1024 + t * 4; }
  else if (bid < 32) { src = Wq; dst = W16 + C4_ * C_;      idx = (bid - 16) * 1024 + t * 4; }
  else               { src = Wv; dst = W16 + 2 * C4_ * C_;  idx = (bid - 32) * 1024 + t * 4; }
  f4 v = *reinterpret_cast<const f4*>(src + idx);
  half4 h;
#pragma unroll
  for (int i = 0; i < 4; ++i) h[i] = (_Float16)v[i];
  *reinterpret_cast<half4*>(dst + idx) = h;
}

// ---------------------------------------------------------------------------
// Kernel 1: Q/K/V projections. Pixel-octet tiles (8w x 8h), dense V stores
// (R10 epilogue, WRITE_SIZE verified clean at 196 MB). Changes this round:
//  * single-F drain pipeline (R8-proven ordering) -> LDS 25.6 KB
//  * __launch_bounds__(256,4): first round not self-capped at 3 blocks/CU
//  * srcsel interleaved on low bid bit (heavy KV and light Q blocks mixed)
// Block map: xcd=bid&7, srcsel=(bid>>3)&1, wtlow=(bid>>4)&1, rest=bid>>5:
//   wt = xcd*2+wtlow (w-stripe per XCD), h8 = rest&15, b = rest>>4.
// ---------------------------------------------------------------------------
__device__ __forceinline__ const half8* afragq(const u16* __restrict__ T,
                                               int prow, int ksl, int lg) {
  int oct = (ksl * 4 + lg) ^ ((prow >> 2) & 7);
  return reinterpret_cast<const half8*>(&T[prow * T_S + oct * 8]);
}

__device__ __forceinline__ const half8* whfrag(const u16* __restrict__ Wm16,
                                               int row, int ks, int lg) {
  return reinterpret_cast<const half8*>(Wm16 + (size_t)row * C_ + ks * 32 + lg * 8);
}

__global__ void __launch_bounds__(256, 4) qkv_kernel(
    const float* __restrict__ flow, const float* __restrict__ de_out,
    const u16* __restrict__ W16,
    const float* __restrict__ bq, const float* __restrict__ bk,
    const float* __restrict__ bv,
    u16* __restrict__ Qws, u16* __restrict__ Kws, u16* __restrict__ Vws) {
  __shared__ __align__(16) unsigned char ldsraw[16384 + 64 * T_S * 2];  // 25600 B
  float* F = reinterpret_cast<float*>(ldsraw);            // [64 c][8 h][8 w] fp32
  u16*   T = reinterpret_cast<u16*>(ldsraw + 16384);      // [64 p][72] fp16 quarter
  u16*   O = reinterpret_cast<u16*>(ldsraw);              // [64 p][72] out tile

  const int t    = threadIdx.x;
  const int bid  = blockIdx.x;
  const int xcd    = bid & 7;
  const int srcsel = (bid >> 3) & 1;
  const int wtlow  = (bid >> 4) & 1;
  const int rest   = bid >> 5;           // [0,256)
  const int wt     = xcd * 2 + wtlow;    // [0,16) : w in [wt*8, wt*8+8)
  const int h8     = rest & 15;          // h in [h8*8, h8*8+8)
  const int b      = rest >> 4;          // [0,16)
  const int lane = t & 63;
  const int wv   = t >> 6;
  const int col  = lane & 15;
  const int lg   = lane >> 4;

  const u16* Wk16 = W16;
  const u16* Wq16 = W16 + C4_ * C_;
  const u16* Wv16 = W16 + 2 * C4_ * C_;

  const float* src = (srcsel ? de_out : flow) +
                     (size_t)b * C_ * HW_ + (size_t)(h8 * 8) * W_ + wt * 8;

  f32x4 zero = {0.f, 0.f, 0.f, 0.f};
  f32x4 acc0[4];                 // K (srcsel=0) or Q (srcsel=1)
  f32x4 accV[4][4];              // V [c-tile j][m-tile]
#pragma unroll
  for (int i = 0; i < 4; ++i) acc0[i] = zero;
#pragma unroll
  for (int j = 0; j < 4; ++j)
#pragma unroll
    for (int i = 0; i < 4; ++i) accV[j][i] = zero;

  for (int q = 0; q < 4; ++q) {
    // ---- issue this quarter's gloads into F ----
#pragma unroll
    for (int i = 0; i < 4; ++i) {
      const int rr0 = wv * 16 + i * 4;
      gload16(src + (size_t)(q * 64 + rr0 + (lane >> 4)) * HW_ +
                  ((lane >> 1) & 7) * W_ + (lane & 1) * 4,
              F + rr0 * 64);
    }
    asm volatile("s_waitcnt vmcnt(0) lgkmcnt(0)\ns_barrier" ::: "memory");
    __builtin_amdgcn_sched_barrier(0);

    // ---- convert: F[c][hl][w8] fp32 -> T[p = w*8+hl][c_loc] fp16 (octet XOR)
#pragma unroll
    for (int i = 0; i < 2; ++i) {
      const int flat = i * 256 + t;            // [0,512)
      const int cp = flat >> 4;                // c-pair [0,32)
      const int hl = (flat >> 1) & 7;
      const int wq = flat & 1;
      const f4 fa = *reinterpret_cast<const f4*>(&F[(2 * cp) * 64 + hl * 8 + wq * 4]);
      const f4 fb = *reinterpret_cast<const f4*>(&F[(2 * cp + 1) * 64 + hl * 8 + wq * 4]);
      const int c_loc = 2 * cp;
#pragma unroll
      for (int j = 0; j < 4; ++j) {
        const int w = wq * 4 + j;
        const int p = w * 8 + hl;
        const int oct = (cp >> 2) ^ ((p >> 2) & 7);
        uint32_t pk = (uint32_t)f16_rn(fa[j]) | ((uint32_t)f16_rn(fb[j]) << 16);
        *reinterpret_cast<uint32_t*>(&T[p * T_S + oct * 8 + (c_loc & 7)]) = pk;
      }
    }
    asm volatile("s_waitcnt lgkmcnt(0)\ns_barrier" ::: "memory");
    __builtin_amdgcn_sched_barrier(0);

    // ---- MFMA this quarter's two k-chunks ----
#pragma unroll
    for (int ksl = 0; ksl < 2; ++ksl) {
      const int ks = 2 * q + ksl;
      if (srcsel == 0) {
        const half8 bK = *whfrag(Wk16, wv * 16 + col, ks, lg);
        half8 bV[4];
#pragma unroll
        for (int j = 0; j < 4; ++j)
          bV[j] = *whfrag(Wv16, (wv * 4 + j) * 16 + col, ks, lg);
#pragma unroll
        for (int mt = 0; mt < 4; ++mt) {
          const half8 afr = *afragq(T, mt * 16 + col, ksl, lg);
          acc0[mt] = __builtin_amdgcn_mfma_f32_16x16x32_f16(afr, bK, acc0[mt], 0, 0, 0);
#pragma unroll
          for (int j = 0; j < 4; ++j)
            accV[j][mt] =
                __builtin_amdgcn_mfma_f32_16x16x32_f16(afr, bV[j], accV[j][mt], 0, 0, 0);
        }
      } else {
        const half8 bQ = *whfrag(Wq16, wv * 16 + col, ks, lg);
#pragma unroll
        for (int mt = 0; mt < 4; ++mt) {
          const half8 afr = *afragq(T, mt * 16 + col, ksl, lg);
          acc0[mt] = __builtin_amdgcn_mfma_f32_16x16x32_f16(afr, bQ, acc0[mt], 0, 0, 0);
        }
      }
    }
    // next-quarter gload overwrites F: convert done at barrier above; MFMA's
    // ds_reads drained by each wave's lgkmcnt(0) before the next barrier.
  }

  // ---- epilogue: m = mt*16+lg*4+r -> p = m : w_loc = p>>3, hl = p&7 ----
  if (srcsel == 0) {
    {  // K via LDS O-tile [p][d], then full-coverage half8 runs
      const float bias = bk[wv * 16 + col];
      __syncthreads();
#pragma unroll
      for (int mt = 0; mt < 4; ++mt)
#pragma unroll
        for (int r = 0; r < 4; ++r)
          O[(mt * 16 + lg * 4 + r) * O_S + wv * 16 + col] = f16_rn(acc0[mt][r] + bias);
      __syncthreads();
#pragma unroll
      for (int i = 0; i < 2; ++i) {
        const int item = i * 256 + t;      // [0,512)
        const int p  = item >> 3;          // [0,64)
        const int d0 = (item & 7) * 8;
        *reinterpret_cast<half8*>(
            &Kws[(((size_t)b * W_ + wt * 8 + (p >> 3)) * H_ + h8 * 8 + (p & 7)) * C4_ + d0]) =
            *reinterpret_cast<const half8*>(&O[p * O_S + d0]);
      }
    }
    // V: dense half4 stores (lanes tile 256-B segments)
    {
      const size_t colbase = ((size_t)b * W_ + wt * 8) * 32768;
#pragma unroll
      for (int j = 0; j < 4; ++j) {
        const int co = (wv * 4 + j) * 16 + col;
        const float bias = bv[co];
#pragma unroll
        for (int mt = 0; mt < 4; ++mt) {
          const int w_loc = mt * 2 + (lg >> 1);
          const int hl0   = (lg & 1) * 4;
          half4 pk;
#pragma unroll
          for (int r = 0; r < 4; ++r) pk[r] = (_Float16)(accV[j][mt][r] + bias);
          *reinterpret_cast<half4*>(
              Vws + colbase + (size_t)w_loc * 32768 + (size_t)(h8 * COUT_ + co) * 8 + hl0) = pk;
        }
      }
    }
  } else {
    const float bias = bq[wv * 16 + col];
    __syncthreads();
#pragma unroll
    for (int mt = 0; mt < 4; ++mt)
#pragma unroll
      for (int r = 0; r < 4; ++r)
        O[(mt * 16 + lg * 4 + r) * O_S + wv * 16 + col] = f16_rn(acc0[mt][r] + bias);
    __syncthreads();
#pragma unroll
    for (int i = 0; i < 2; ++i) {
      const int item = i * 256 + t;
      const int p  = item >> 3;
      const int d0 = (item & 7) * 8;
      *reinterpret_cast<half8*>(
          &Qws[(((size_t)b * W_ + wt * 8 + (p >> 3)) * H_ + h8 * 8 + (p & 7)) * C4_ + d0]) =
          *reinterpret_cast<const half8*>(&O[p * O_S + d0]);
    }
  }
}

// ---------------------------------------------------------------------------
// DIAGNOSTIC probe: qkv's staging skeleton ONLY (same grid/LDS/launch-bounds/
// addresses/barrier cadence), 12 quarters = 3 full input passes, no convert,
// no MFMA, no epilogue. Runs AFTER the pipeline; writes to dead Qws scratch.
// Readout: probe_dur/3 >~ 180 us => staging path is qkv's wall;
//          probe_dur/3 <~ 100 us => wall is the convert/MFMA/barrier side.
// ---------------------------------------------------------------------------
__global__ void __launch_bounds__(256, 4) probe_stage_kernel(
    const float* __restrict__ flow, const float* __restrict__ de_out,
    unsigned* __restrict__ scratch) {
  __shared__ __align__(16) unsigned char ldsraw[25600];  // match qkv footprint
  float* F = reinterpret_cast<float*>(ldsraw);
  const int t   = threadIdx.x;
  const int bid = blockIdx.x;
  const int xcd    = bid & 7;
  const int srcsel = (bid >> 3) & 1;
  const int wtlow  = (bid >> 4) & 1;
  const int rest   = bid >> 5;
  const int wt     = xcd * 2 + wtlow;
  const int h8     = rest & 15;
  const int b      = rest >> 4;
  const int lane = t & 63;
  const int wv   = t >> 6;

  const float* src = (srcsel ? de_out : flow) +
                     (size_t)b * C_ * HW_ + (size_t)(h8 * 8) * W_ + wt * 8;

  for (int q = 0; q < 12; ++q) {
    const int cb = (q & 3) * 64;
#pragma unroll
    for (int i = 0; i < 4; ++i) {
      const int rr0 = wv * 16 + i * 4;
      gload16(src + (size_t)(cb + rr0 + (lane >> 4)) * HW_ +
                  ((lane >> 1) & 7) * W_ + (lane & 1) * 4,
              F + rr0 * 64);
    }
    asm volatile("s_waitcnt vmcnt(0) lgkmcnt(0)\ns_barrier" ::: "memory");
    __builtin_amdgcn_sched_barrier(0);
  }
  scratch[(size_t)bid * 256 + t] = __builtin_bit_cast(unsigned, F[t]);
}

// ---------------------------------------------------------------------------
// Kernel 2: per-(b,w)-column attention (unchanged).
// ---------------------------------------------------------------------------
template <int EPI>
__global__ void __launch_bounds__(256) attn_kernel(
    const u16* __restrict__ Qws, const u16* __restrict__ Kws,
    const u16* __restrict__ Vws, u16* __restrict__ out_tmp,
    float* __restrict__ out) {
  __shared__ __align__(16) u16 ldsQK[2 * 128 * QK_S];  // P and epi-tile overlay

  const int t   = threadIdx.x;
  const int bid = blockIdx.x;
  const int sw  = (bid & 7) * 256 + (bid >> 3);  // bijective
  const int b   = sw >> 7;
  const int w   = sw & 127;
  const int lane = t & 63;
  const int wv   = t >> 6;
  const int col  = lane & 15;
  const int lg   = lane >> 4;

  const u16* qc    = Qws + ((size_t)b * W_ + w) * H_ * C4_;
  const u16* kc    = Kws + ((size_t)b * W_ + w) * H_ * C4_;
  const u16* vbase = Vws + (size_t)(b * W_ + w) * 32768;

  u16* ldsQ = ldsQK;
  u16* ldsK = ldsQK + 128 * QK_S;

#pragma unroll
  for (int i = 0; i < 4; ++i) {
    int item = i * 256 + t;
    int hh   = item >> 3;
    int d0   = (item & 7) * 8;
    *reinterpret_cast<half8*>(&ldsQ[hh * QK_S + d0]) =
        *reinterpret_cast<const half8*>(qc + item * 8);
    *reinterpret_cast<half8*>(&ldsK[hh * QK_S + d0]) =
        *reinterpret_cast<const half8*>(kc + item * 8);
  }
  __syncthreads();

  f32x4 zero = {0.f, 0.f, 0.f, 0.f};
  f32x4 e[2][8];
#pragma unroll
  for (int ht = 0; ht < 2; ++ht)
#pragma unroll
    for (int gt = 0; gt < 8; ++gt) e[ht][gt] = zero;

#pragma unroll
  for (int ks = 0; ks < 2; ++ks) {
    half8 aq[2];
#pragma unroll
    for (int ht = 0; ht < 2; ++ht)
      aq[ht] = *reinterpret_cast<const half8*>(
          &ldsQ[(wv * 32 + ht * 16 + col) * QK_S + ks * 32 + lg * 8]);
#pragma unroll
    for (int gt = 0; gt < 8; ++gt) {
      const half8 bk_ = *reinterpret_cast<const half8*>(
          &ldsK[(gt * 16 + col) * QK_S + ks * 32 + lg * 8]);
#pragma unroll
      for (int ht = 0; ht < 2; ++ht)
        e[ht][gt] = __builtin_amdgcn_mfma_f32_16x16x32_f16(aq[ht], bk_, e[ht][gt], 0, 0, 0);
    }
  }
  __syncthreads();  // Q/K dead -> region becomes P

  u16* ldsP = ldsQK + wv * 32 * P_S;  // wave-private slice

#pragma unroll
  for (int ht = 0; ht < 2; ++ht)
#pragma unroll
    for (int r = 0; r < 4; ++r) {
      float m = -1e30f;
#pragma unroll
      for (int gt = 0; gt < 8; ++gt) m = fmaxf(m, e[ht][gt][r]);
#pragma unroll
      for (int off = 1; off < 16; off <<= 1) m = fmaxf(m, __shfl_xor(m, off));
      float s = 0.f;
#pragma unroll
      for (int gt = 0; gt < 8; ++gt) {
        float p = __expf(e[ht][gt][r] - m);
        e[ht][gt][r] = p;
        s += p;
      }
#pragma unroll
      for (int off = 1; off < 16; off <<= 1) s += __shfl_xor(s, off);
      const float inv = 1.f / s;
      const int hh = ht * 16 + lg * 4 + r;
#pragma unroll
      for (int gt = 0; gt < 8; ++gt)
        ldsP[hh * P_S + gt * 16 + col] = f16_rn(e[ht][gt][r] * inv);
    }

  f32x4 o[2][16];
#pragma unroll
  for (int ht = 0; ht < 2; ++ht)
#pragma unroll
    for (int ct = 0; ct < 16; ++ct) o[ht][ct] = zero;

#pragma unroll
  for (int ks = 0; ks < 4; ++ks) {
    half8 ap[2];
#pragma unroll
    for (int ht = 0; ht < 2; ++ht)
      ap[ht] = *reinterpret_cast<const half8*>(
          &ldsP[(ht * 16 + col) * P_S + ks * 32 + lg * 8]);
#pragma unroll
    for (int ct = 0; ct < 16; ++ct) {
      const half8 bv_ = *reinterpret_cast<const half8*>(
          vbase + ((ks * 4 + lg) * COUT_ + ct * 16 + col) * 8);
#pragma unroll
      for (int ht = 0; ht < 2; ++ht)
        o[ht][ct] = __builtin_amdgcn_mfma_f32_16x16x32_f16(ap[ht], bv_, o[ht][ct], 0, 0, 0);
    }
  }

  if (EPI == 1) {
    u16* ldsX = ldsQK;  // reuse
    u16* dst_col = out_tmp + ((size_t)(b * W_ + w) << 15);
#pragma unroll
    for (int ctg = 0; ctg < 4; ++ctg) {
      __syncthreads();
#pragma unroll
      for (int j = 0; j < 4; ++j) {
        const int ct    = ctg * 4 + j;
        const int c_loc = j * 16 + col;
#pragma unroll
        for (int ht = 0; ht < 2; ++ht) {
          const int hbase = wv * 32 + ht * 16 + lg * 4;
          half4 pk;
#pragma unroll
          for (int r = 0; r < 4; ++r) pk[r] = (_Float16)o[ht][ct][r];
          *reinterpret_cast<half4*>(&ldsX[c_loc * XP_S + hbase]) = pk;
        }
      }
      __syncthreads();
      const int c_loc = t >> 2;
      const int h0    = (t & 3) * 32;
      u16* dp = dst_col + (ctg * 64 + c_loc) * 128 + h0;
#pragma unroll
      for (int k = 0; k < 4; ++k)
        *reinterpret_cast<half8*>(dp + k * 8) =
            *reinterpret_cast<const half8*>(&ldsX[c_loc * XP_S + h0 + k * 8]);
    }
  } else {
    float* outp = out + (size_t)b * COUT_ * HW_ + w;
#pragma unroll
    for (int ht = 0; ht < 2; ++ht)
#pragma unroll
      for (int ct = 0; ct < 16; ++ct)
#pragma unroll
        for (int r = 0; r < 4; ++r) {
          int hrow = wv * 32 + ht * 16 + lg * 4 + r;
          int c = ct * 16 + col;
          outp[((size_t)c * H_ + hrow) * W_] = o[ht][ct][r];
        }
  }
}

// ---------------------------------------------------------------------------
// Kernel 3: out_tmp[b][w][f] fp16 -> out[b][f][w] fp32 (unchanged).
// ---------------------------------------------------------------------------
__global__ void __launch_bounds__(256) transpose_kernel(
    const u16* __restrict__ T, float* __restrict__ out) {
  __shared__ float lds[64 * 132];
  const int t   = threadIdx.x;
  const int bid = blockIdx.x;
  const int b   = bid >> 9;
  const int ft  = bid & 511;  // f-tile of 64

  {
    const int w  = t >> 1;
    const int fo = (t & 1) * 32;
    const u16* src = T + ((size_t)(b * W_ + w) << 15) + ft * 64 + fo;
#pragma unroll
    for (int k = 0; k < 4; ++k) {
      half8 v = *reinterpret_cast<const half8*>(src + k * 8);
#pragma unroll
      for (int e = 0; e < 8; ++e)
        lds[(fo + k * 8 + e) * 132 + w] = (float)v[e];
    }
  }
  __syncthreads();
  {
    const int f_loc = t >> 2;
    const int w0    = (t & 3) * 32;
    float* dst = out + (size_t)b * (COUT_ * HW_) + (size_t)(ft * 64 + f_loc) * 128 + w0;
#pragma unroll
    for (int k = 0; k < 8; ++k) {
      f4 v4;
#pragma unroll
      for (int e = 0; e < 4; ++e) v4[e] = lds[f_loc * 132 + w0 + k * 4 + e];
      *reinterpret_cast<f4*>(dst + k * 4) = v4;
    }
  }
}

extern "C" void kernel_launch(void* const* d_in, const int* in_sizes, int n_in,
                              void* d_out, int out_size, void* d_ws, size_t ws_size,
                              hipStream_t stream) {
  const float* flow   = (const float*)d_in[0];
  const float* de_out = (const float*)d_in[1];
  const float* Wq = (const float*)d_in[2];
  const float* bq = (const float*)d_in[3];
  const float* Wk = (const float*)d_in[4];
  const float* bk = (const float*)d_in[5];
  const float* Wv = (const float*)d_in[6];
  const float* bv = (const float*)d_in[7];
  float* out = (float*)d_out;

  u16* Qws = (u16*)d_ws;                 // [b][w][h][d]            fp16
  u16* Kws = Qws + Q_ELEMS;              // [b][w][h][d]            fp16
  u16* Vws = Kws + Q_ELEMS;              // [b][w][g>>3][c][g&7]    fp16
  u16* W16 = Vws + V_ELEMS;              // [Wk16|Wq16|Wv16]        fp16
  u16* Tws = W16 + W16_ELEMS;            // [b][w][c][h]            fp16

  wconv_kernel<<<96, 256, 0, stream>>>(Wk, Wq, Wv, W16);
  qkv_kernel<<<8192, 256, 0, stream>>>(flow, de_out, W16, bq, bk, bv,
                                       Qws, Kws, Vws);
  if (ws_size >= (size_t)WS_NEED) {
    attn_kernel<1><<<B_ * W_, 256, 0, stream>>>(Qws, Kws, Vws, Tws, out);
    transpose_kernel<<<B_ * 512, 256, 0, stream>>>(Tws, out);
  } else {
    attn_kernel<0><<<B_ * W_, 256, 0, stream>>>(Qws, Kws, Vws, Tws, out);
  }
  // diagnostic: staging skeleton, 3 input passes, writes to dead Qws scratch
  probe_stage_kernel<<<8192, 256, 0, stream>>>(flow, de_out, (unsigned*)Qws);
}

// Round 12
// 694.814 us; speedup vs baseline: 1.7915x; 1.7915x over previous
//
#include <hip/hip_runtime.h>
#include <cstdint>
#include <cstddef>

typedef unsigned short u16;
using half4 = __attribute__((ext_vector_type(4))) _Float16;
using half8 = __attribute__((ext_vector_type(8))) _Float16;
using f32x4 = __attribute__((ext_vector_type(4))) float;
using f4    = __attribute__((ext_vector_type(4))) float;
using u32x4 = __attribute__((ext_vector_type(4))) uint32_t;

#define B_    16
#define C_    256
#define H_    128
#define W_    128
#define C4_   64
#define COUT_ 256
#define HW_   (H_ * W_)

#define QK_S  72     // fused Q/K [h][d]: 64 + 8 pad
#define P_S   136    // fused P [h][g]: 128 + 8 pad
#define XP_S  140    // fused epilogue tile [c][h]
#define VT_SO 2056   // fused V^T u16 per g-octet: 256*8 + 8 pad (lg groups 4 banks apart)

#define XT_HALF   ((size_t)B_ * W_ * H_ * C_)                   // 67,108,864 elems/src
#define W16_ELEMS ((size_t)(C4_ * C_ + C4_ * C_ + COUT_ * C_))  // 98,304
#define WS_NEED   ((2 * XT_HALF + W16_ELEMS) * 2)               // 268,632,064 B (< proven 335 MB)

__device__ __forceinline__ u16 f16_rn(float f) {
  _Float16 h = (_Float16)f;   // RN
  return __builtin_bit_cast(u16, h);
}

// ---------------------------------------------------------------------------
// Kernel 0: one-time fp32 -> fp16 weight conversion into ws.
// ---------------------------------------------------------------------------
__global__ void __launch_bounds__(256) wconv_kernel(
    const float* __restrict__ Wk, const float* __restrict__ Wq,
    const float* __restrict__ Wv, u16* __restrict__ W16) {
  const int bid = blockIdx.x;
  const int t   = threadIdx.x;
  const float* src;
  u16* dst;
  int idx;
  if (bid < 16)      { src = Wk; dst = W16;                 idx = bid * 1024 + t * 4; }
  else if (bid < 32) { src = Wq; dst = W16 + C4_ * C_;      idx = (bid - 16) * 1024 + t * 4; }
  else               { src = Wv; dst = W16 + 2 * C4_ * C_;  idx = (bid - 32) * 1024 + t * 4; }
  f4 v = *reinterpret_cast<const f4*>(src + idx);
  half4 h;
#pragma unroll
  for (int i = 0; i < 4; ++i) h[i] = (_Float16)v[i];
  *reinterpret_cast<half4*>(dst + idx) = h;
}

// ---------------------------------------------------------------------------
// Kernel 1: xt — streaming transpose-convert.
// in fp32 [b][c][h][w] -> XT fp16 [src][b][w][h][c]  (c contiguous per pixel).
// Block = (src, b, h, c-quarter): reads 64 rows x 512 B (fully dense), writes
// 128 chunks of 128 B (2 full lines each). LDS pair-packed u32 [w][c2^swz].
// ---------------------------------------------------------------------------
__global__ void __launch_bounds__(256) xt_kernel(
    const float* __restrict__ flow, const float* __restrict__ de_out,
    u16* __restrict__ XT) {
  __shared__ uint32_t Lw[128 * 36];   // 18,432 B
  const int t   = threadIdx.x;
  const int bid = blockIdx.x;
  const int cq  = bid & 3;
  const int h   = (bid >> 2) & 127;
  const int b   = (bid >> 9) & 15;
  const int src = bid >> 13;

  const float* in = (src ? de_out : flow) +
                    (size_t)b * C_ * HW_ + (size_t)(cq * 64) * HW_ + (size_t)h * W_;

  // read: 32 consecutive lanes cover one full 512-B c-row; pack c-pairs to u32
#pragma unroll
  for (int it = 0; it < 4; ++it) {
    const int c2 = it * 8 + (t >> 5);        // c-pair [0,32)
    const int w4 = (t & 31) * 4;
    const float* r0 = in + (size_t)(2 * c2) * HW_ + w4;
    f4 va = *reinterpret_cast<const f4*>(r0);
    f4 vb = *reinterpret_cast<const f4*>(r0 + HW_);
#pragma unroll
    for (int j = 0; j < 4; ++j) {
      const int w  = w4 + j;
      const int sw = ((w >> 2) & 7) * 4;     // keeps 4-aligned blocks intact
      Lw[w * 36 + (c2 ^ sw)] =
          (uint32_t)f16_rn(va[j]) | ((uint32_t)f16_rn(vb[j]) << 16);
    }
  }
  __syncthreads();

  // write: thread -> (w, c-half): 32 c-elems = 64 B contiguous; lane pairs
  // (t even/odd) cover 64 B each -> full-line dense stores.
  {
    const int w     = t >> 1;
    const int chalf = t & 1;
    const int sw    = ((w >> 2) & 7) * 4;
    u16* dst = XT + (size_t)src * XT_HALF +
               (((size_t)(b * W_ + w)) * H_ + h) * C_ + cq * 64 + chalf * 32;
#pragma unroll
    for (int k = 0; k < 4; ++k) {
      const int c2b = (chalf * 16 + k * 4) ^ sw;
      u32x4 v = *reinterpret_cast<const u32x4*>(&Lw[w * 36 + c2b]);
      *reinterpret_cast<u32x4*>(dst + k * 8) = v;
    }
  }
}

// ---------------------------------------------------------------------------
// Kernel 2: fused QKV-projection + column attention. Block = (b,w), 8 waves.
// A-fragments (pixel rows, 8 consecutive c) read DIRECTLY from XT global;
// K,V from XT_flow and Q from XT_de -> LDS; then the R4-proven attn sequence.
// out_tmp[b][w][c][h] ALIASES XT_de[b][w] (each block overwrites its own
// column after its last read of it).
// ---------------------------------------------------------------------------
__device__ __forceinline__ const half8* whfrag(const u16* __restrict__ Wm16,
                                               int row, int ks, int lg) {
  return reinterpret_cast<const half8*>(Wm16 + (size_t)row * C_ + ks * 32 + lg * 8);
}

__global__ void __launch_bounds__(512) fused_kernel(
    u16* XTbuf,  // NOT restrict: out region aliases XT_de
    const u16* __restrict__ W16,
    const float* __restrict__ bq, const float* __restrict__ bk,
    const float* __restrict__ bv) {
  __shared__ __align__(16) u16 lds[2 * 128 * QK_S + 16 * VT_SO];  // 102,656 B
  u16* ldsQ  = lds;                       // [128][72]
  u16* ldsK  = lds + 128 * QK_S;          // [128][72]
  u16* ldsVT = lds + 2 * 128 * QK_S;      // [16 goct][2056]

  const int t   = threadIdx.x;
  const int bid = blockIdx.x;
  const int sw  = (bid & 7) * 256 + (bid >> 3);  // bijective (2048 % 8 == 0)
  const int b   = sw >> 7;
  const int w   = sw & 127;
  const int lane = t & 63;
  const int wv   = t >> 6;        // 0..7 : wave owns h-rows [wv*16, wv*16+16)
  const int col  = lane & 15;
  const int lg   = lane >> 4;

  const u16* xf = XTbuf + ((size_t)(b * W_) + w) * (H_ * C_);            // flow col
  u16*       xd = XTbuf + XT_HALF + ((size_t)(b * W_) + w) * (H_ * C_);  // de col / out

  const u16* Wk16 = W16;
  const u16* Wq16 = W16 + C4_ * C_;
  const u16* Wv16 = W16 + 2 * C4_ * C_;

  f32x4 zero = {0.f, 0.f, 0.f, 0.f};

  // ---- K + V projections: A = flow pixels (rows h = wv*16+col) ----
  half8 af[8];
#pragma unroll
  for (int ks = 0; ks < 8; ++ks)
    af[ks] = *reinterpret_cast<const half8*>(
        xf + (size_t)(wv * 16 + col) * C_ + ks * 32 + lg * 8);
  {
    f32x4 acck[4];
#pragma unroll
    for (int i = 0; i < 4; ++i) acck[i] = zero;
#pragma unroll
    for (int ks = 0; ks < 8; ++ks)
#pragma unroll
      for (int nt = 0; nt < 4; ++nt)
        acck[nt] = __builtin_amdgcn_mfma_f32_16x16x32_f16(
            af[ks], *whfrag(Wk16, nt * 16 + col, ks, lg), acck[nt], 0, 0, 0);
#pragma unroll
    for (int nt = 0; nt < 4; ++nt) {
      const float bias = bk[nt * 16 + col];
#pragma unroll
      for (int r = 0; r < 4; ++r)
        ldsK[(wv * 16 + lg * 4 + r) * QK_S + nt * 16 + col] =
            f16_rn(acck[nt][r] + bias);
    }
  }
  {
    f32x4 accv[16];
#pragma unroll
    for (int i = 0; i < 16; ++i) accv[i] = zero;
#pragma unroll
    for (int ks = 0; ks < 8; ++ks)
#pragma unroll
      for (int nt = 0; nt < 16; ++nt)
        accv[nt] = __builtin_amdgcn_mfma_f32_16x16x32_f16(
            af[ks], *whfrag(Wv16, nt * 16 + col, ks, lg), accv[nt], 0, 0, 0);
    // VT[(g>>3)][c][g&7]: g = wv*16 + lg*4 + r -> goct = wv*2+(lg>>1), hl0=(lg&1)*4
    const int goct = wv * 2 + (lg >> 1);
    const int hl0  = (lg & 1) * 4;
#pragma unroll
    for (int nt = 0; nt < 16; ++nt) {
      const int c = nt * 16 + col;
      const float bias = bv[c];
      half4 pk;
#pragma unroll
      for (int r = 0; r < 4; ++r) pk[r] = (_Float16)(accv[nt][r] + bias);
      *reinterpret_cast<half4*>(&ldsVT[goct * VT_SO + c * 8 + hl0]) = pk;
    }
  }
  // ---- Q projection: A = de pixels ----
  {
#pragma unroll
    for (int ks = 0; ks < 8; ++ks)
      af[ks] = *reinterpret_cast<const half8*>(
          xd + (size_t)(wv * 16 + col) * C_ + ks * 32 + lg * 8);
    f32x4 accq[4];
#pragma unroll
    for (int i = 0; i < 4; ++i) accq[i] = zero;
#pragma unroll
    for (int ks = 0; ks < 8; ++ks)
#pragma unroll
      for (int nt = 0; nt < 4; ++nt)
        accq[nt] = __builtin_amdgcn_mfma_f32_16x16x32_f16(
            af[ks], *whfrag(Wq16, nt * 16 + col, ks, lg), accq[nt], 0, 0, 0);
#pragma unroll
    for (int nt = 0; nt < 4; ++nt) {
      const float bias = bq[nt * 16 + col];
#pragma unroll
      for (int r = 0; r < 4; ++r)
        ldsQ[(wv * 16 + lg * 4 + r) * QK_S + nt * 16 + col] =
            f16_rn(accq[nt][r] + bias);
    }
  }
  __syncthreads();   // Q, K, VT complete

  // ---- E = Q K^T : wave's 16 q-rows x 128 g ----
  f32x4 e[8];
#pragma unroll
  for (int gt = 0; gt < 8; ++gt) e[gt] = zero;
#pragma unroll
  for (int ks = 0; ks < 2; ++ks) {
    const half8 aq = *reinterpret_cast<const half8*>(
        &ldsQ[(wv * 16 + col) * QK_S + ks * 32 + lg * 8]);
#pragma unroll
    for (int gt = 0; gt < 8; ++gt) {
      const half8 bkf = *reinterpret_cast<const half8*>(
          &ldsK[(gt * 16 + col) * QK_S + ks * 32 + lg * 8]);
      e[gt] = __builtin_amdgcn_mfma_f32_16x16x32_f16(aq, bkf, e[gt], 0, 0, 0);
    }
  }
  __syncthreads();   // Q/K dead -> region becomes P

  u16* ldsP = lds;   // [128][P_S] (34,816 B <= Q+K region)
#pragma unroll
  for (int r = 0; r < 4; ++r) {
    float m = -1e30f;
#pragma unroll
    for (int gt = 0; gt < 8; ++gt) m = fmaxf(m, e[gt][r]);
#pragma unroll
    for (int off = 1; off < 16; off <<= 1) m = fmaxf(m, __shfl_xor(m, off));
    float s = 0.f;
#pragma unroll
    for (int gt = 0; gt < 8; ++gt) {
      float p = __expf(e[gt][r] - m);
      e[gt][r] = p;
      s += p;
    }
#pragma unroll
    for (int off = 1; off < 16; off <<= 1) s += __shfl_xor(s, off);
    const float inv = 1.f / s;
    const int hh = wv * 16 + lg * 4 + r;
#pragma unroll
    for (int gt = 0; gt < 8; ++gt)
      ldsP[hh * P_S + gt * 16 + col] = f16_rn(e[gt][r] * inv);
  }
  // P rows are wave-private: in-wave ds ordering suffices before PV.

  // ---- O = P V : wave's 16 h-rows x 256 c ----
  f32x4 o[16];
#pragma unroll
  for (int ct = 0; ct < 16; ++ct) o[ct] = zero;
#pragma unroll
  for (int ks = 0; ks < 4; ++ks) {
    const half8 ap = *reinterpret_cast<const half8*>(
        &ldsP[(wv * 16 + col) * P_S + ks * 32 + lg * 8]);
#pragma unroll
    for (int ct = 0; ct < 16; ++ct) {
      const half8 bvf = *reinterpret_cast<const half8*>(
          &ldsVT[(ks * 4 + lg) * VT_SO + (ct * 16 + col) * 8]);
      o[ct] = __builtin_amdgcn_mfma_f32_16x16x32_f16(ap, bvf, o[ct], 0, 0, 0);
    }
  }

  // ---- epilogue: LDS-transpose 64c x 128h tiles -> fp16 out col [c][h] ----
  // (overwrites xd == this block's XT_de column; its last read was Q phase)
  u16* ldsX = lds;
  u16* dst_col = xd;
#pragma unroll
  for (int ctg = 0; ctg < 4; ++ctg) {
    __syncthreads();   // P dead (first iter) / previous tile consumed
#pragma unroll
    for (int j = 0; j < 4; ++j) {
      const int ct    = ctg * 4 + j;
      const int c_loc = j * 16 + col;
      half4 pk;
#pragma unroll
      for (int r = 0; r < 4; ++r) pk[r] = (_Float16)o[ct][r];
      *reinterpret_cast<half4*>(&ldsX[c_loc * XP_S + wv * 16 + lg * 4]) = pk;
    }
    __syncthreads();
    const int c_loc = t >> 3;          // [0,64)
    const int h0    = (t & 7) * 16;
    u16* dp = dst_col + (ctg * 64 + c_loc) * 128 + h0;
    *reinterpret_cast<half8*>(dp) =
        *reinterpret_cast<const half8*>(&ldsX[c_loc * XP_S + h0]);
    *reinterpret_cast<half8*>(dp + 8) =
        *reinterpret_cast<const half8*>(&ldsX[c_loc * XP_S + h0 + 8]);
  }
}

// ---------------------------------------------------------------------------
// Kernel 3: out_tmp[b][w][f] fp16 -> out[b][f][w] fp32   (f = c*128 + h)
// ---------------------------------------------------------------------------
__global__ void __launch_bounds__(256) transpose_kernel(
    const u16* __restrict__ T, float* __restrict__ out) {
  __shared__ float lds[64 * 132];
  const int t   = threadIdx.x;
  const int bid = blockIdx.x;
  const int b   = bid >> 9;
  const int ft  = bid & 511;  // f-tile of 64

  {
    const int w  = t >> 1;
    const int fo = (t & 1) * 32;
    const u16* src = T + ((size_t)(b * W_ + w) << 15) + ft * 64 + fo;
#pragma unroll
    for (int k = 0; k < 4; ++k) {
      half8 v = *reinterpret_cast<const half8*>(src + k * 8);
#pragma unroll
      for (int e = 0; e < 8; ++e)
        lds[(fo + k * 8 + e) * 132 + w] = (float)v[e];
    }
  }
  __syncthreads();
  {
    const int f_loc = t >> 2;
    const int w0    = (t & 3) * 32;
    float* dst = out + (size_t)b * (COUT_ * HW_) + (size_t)(ft * 64 + f_loc) * 128 + w0;
#pragma unroll
    for (int k = 0; k < 8; ++k) {
      f4 v4;
#pragma unroll
      for (int e = 0; e < 4; ++e) v4[e] = lds[f_loc * 132 + w0 + k * 4 + e];
      *reinterpret_cast<f4*>(dst + k * 4) = v4;
    }
  }
}

extern "C" void kernel_launch(void* const* d_in, const int* in_sizes, int n_in,
                              void* d_out, int out_size, void* d_ws, size_t ws_size,
                              hipStream_t stream) {
  const float* flow   = (const float*)d_in[0];
  const float* de_out = (const float*)d_in[1];
  const float* Wq = (const float*)d_in[2];
  const float* bq = (const float*)d_in[3];
  const float* Wk = (const float*)d_in[4];
  const float* bk = (const float*)d_in[5];
  const float* Wv = (const float*)d_in[6];
  const float* bv = (const float*)d_in[7];
  float* out = (float*)d_out;

  u16* XTws = (u16*)d_ws;                 // [src][b][w][h][c] fp16; de half
                                          // doubles as out_tmp [b][w][c][h]
  u16* W16  = XTws + 2 * XT_HALF;         // [Wk16|Wq16|Wv16] fp16
  // total ws use: 268,632,064 B (< 335 MB bound proven satisfied in R4-R10)

  wconv_kernel<<<96, 256, 0, stream>>>(Wk, Wq, Wv, W16);
  xt_kernel<<<2 * B_ * H_ * 4, 256, 0, stream>>>(flow, de_out, XTws);
  fused_kernel<<<B_ * W_, 512, 0, stream>>>(XTws, W16, bq, bk, bv);
  transpose_kernel<<<B_ * 512, 256, 0, stream>>>(XTws + XT_HALF, out);
}